// Round 15
// baseline (987.476 us; speedup 1.0000x reference)
//
#include <hip/hip_runtime.h>
#include <cmath>
#include <cstddef>

#define FGK_NN   20000
#define FGK_NE   320000
#define FGK_H    128
#define FGK_P    16
#define FGK_TRI  136
#define FGK_F    152
#define FGK_EPB  16
#define FGK_YP   153          // sY row stride (>=152; 26.6 KB total -> 6 blocks/CU)

typedef short  s16x8 __attribute__((ext_vector_type(8)));
typedef float  f32x4 __attribute__((ext_vector_type(4)));

__device__ __forceinline__ unsigned short fgk_f2b(float f) {   // RNE f32->bf16 bits
    unsigned int u = __float_as_uint(f);
    return (unsigned short)((u + 0x7FFFu + ((u >> 16) & 1u)) >> 16);
}
__device__ __forceinline__ float fgk_u2f(unsigned short u) {
    return __uint_as_float(((unsigned int)u) << 16);
}

__global__ void FishnetGCN_62096637165586_kernel() {}

__global__ void fgkZero(float* acc) {
    int i = blockIdx.x * blockDim.x + threadIdx.x;
    if (i < FGK_NN * (FGK_P + FGK_TRI)) acc[i] = 0.f;
}
__global__ void fgkZeroI(int* p, int n) {
    int i = blockIdx.x * blockDim.x + threadIdx.x;
    if (i < n) p[i] = 0;
}
// ---- dst-sort: histogram -> block scan -> scatter (edge_index constant) ----
__global__ void fgkHist(const int* __restrict__ dst, int* __restrict__ hist) {
    int e = blockIdx.x * blockDim.x + threadIdx.x;
    if (e < FGK_NE) atomicAdd(&hist[dst[e]], 1);
}
__global__ void fgkScan(const int* __restrict__ hist, int* __restrict__ cursor)
{
    __shared__ int sWave[16];
    __shared__ int sRun;
    int t = threadIdx.x;             // 1024
    int lane = t & 63, wv = t >> 6;
    if (t == 0) sRun = 0;
    __syncthreads();
    for (int base = 0; base < FGK_NN; base += 1024) {
        int idx = base + t;
        int v = (idx < FGK_NN) ? hist[idx] : 0;
        int sc = v;
#pragma unroll
        for (int off = 1; off < 64; off <<= 1) {
            int u = __shfl_up(sc, off);
            if (lane >= off) sc += u;
        }
        if (lane == 63) sWave[wv] = sc;
        __syncthreads();
        if (wv == 0 && lane < 16) {
            int w = sWave[lane];
#pragma unroll
            for (int off = 1; off < 16; off <<= 1) {
                int u = __shfl_up(w, off, 16);
                if (lane >= off) w += u;
            }
            sWave[lane] = w;
        }
        __syncthreads();
        int waveOff = (wv == 0) ? 0 : sWave[wv - 1];
        int run = sRun;
        if (idx < FGK_NN) cursor[idx] = run + waveOff + sc - v;   // exclusive
        __syncthreads();
        if (t == 1023) sRun = run + sWave[15];
        __syncthreads();
    }
}
__global__ void fgkScatterE(const int* __restrict__ dst, int* __restrict__ cursor,
                            int* __restrict__ perm) {
    int e = blockIdx.x * blockDim.x + threadIdx.x;
    if (e < FGK_NE) {
        int pos = atomicAdd(&cursor[dst[e]], 1);
        perm[pos] = e;
    }
}

// Generic prepack of W[K,N] (row-major) into MFMA B-fragment order, bf16 hi/lo.
__global__ void fgkPrepW(const float* __restrict__ W, int K, int N,
                         unsigned short* __restrict__ hi,
                         unsigned short* __restrict__ lo)
{
    int chunks = K >> 5;
    int b = blockIdx.x;
    int nt = b / chunks, c = b - nt * chunks;
    int lane = threadIdx.x;
    int n = nt * 16 + (lane & 15);
    int g = lane >> 4;
    size_t base = ((size_t)b * 64 + lane) * 8;
#pragma unroll
    for (int j = 0; j < 8; ++j) {
        int k = c * 32 + g * 8 + j;
        float v = (n < N) ? W[(size_t)k * N + n] : 0.f;
        unsigned short hb = fgk_f2b(v);
        unsigned short lb = fgk_f2b(v - fgk_u2f(hb));
        hi[base + j] = hb;
        lo[base + j] = lb;
    }
}

// hin = x @ W[8,128] + b
__global__ void fgkEnc(const float* __restrict__ xin,
                       const float* __restrict__ wenc,
                       const float* __restrict__ benc,
                       float* __restrict__ hin)
{
    int idx = blockIdx.x * blockDim.x + threadIdx.x;
    if (idx >= FGK_NN * FGK_H) return;
    int n = idx >> 7, j = idx & 127;
    float acc = benc[j];
    const float* xp = xin + (size_t)n * 8;
#pragma unroll
    for (int k = 0; k < 8; k++) acc += xp[k] * wenc[k * FGK_H + j];
    hin[idx] = acc;
}

// hin = relu(layernorm(h, g, b)) over 128
__global__ void fgkLn(const float* __restrict__ hsrc,
                      const float* __restrict__ gamma,
                      const float* __restrict__ beta,
                      float* __restrict__ hin)
{
    int n = blockIdx.x, t = threadIdx.x;   // block = 128
    float v = hsrc[(size_t)n * FGK_H + t];
    float s1 = v, s2 = v * v;
#pragma unroll
    for (int off = 32; off; off >>= 1) { s1 += __shfl_down(s1, off); s2 += __shfl_down(s2, off); }
    __shared__ float red[4];
    int wid = t >> 6, lane = t & 63;
    if (lane == 0) { red[wid] = s1; red[2 + wid] = s2; }
    __syncthreads();
    float mu = (red[0] + red[1]) * (1.f / FGK_H);
    float var = (red[2] + red[3]) * (1.f / FGK_H) - mu * mu;
    float rstd = rsqrtf(var + 1e-5f);
    float o = (v - mu) * rstd * gamma[t] + beta[t];
    hin[(size_t)n * FGK_H + t] = fmaxf(o, 0.f);
}

// edge (sorted by dst): bulk hin prefetch -> frags ; y=MFMA ; L->frags ;
// Fe=MFMA ; per-slot LDS reduction ; ~152 atomics per distinct dst
__global__ void __launch_bounds__(256)
fgkEdge(const float* __restrict__ eatt,
        const int* __restrict__ srcIdx,
        const int* __restrict__ dstIdx,
        const int* __restrict__ perm,
        const float* __restrict__ eew,
        const float* __restrict__ eeb,
        const unsigned short* __restrict__ bHi,
        const unsigned short* __restrict__ bLo,
        const float* __restrict__ a1b,
        const float* __restrict__ hin,
        float* __restrict__ snAcc,
        float* __restrict__ fnAcc)
{
    __shared__ float uni[4096];                   // 16 KB: A-frags, then L-frags
    __shared__ float sY[FGK_EPB][FGK_YP];         // 9.56 KB: hin rows -> y -> sTri
    __shared__ int sE[FGK_EPB], sSrc[FGK_EPB], sDst[FGK_EPB];
    __shared__ int sStart[FGK_EPB], sEnd[FGK_EPB], sDstSlot[FGK_EPB];
    __shared__ int sNS;
    unsigned short* aH = (unsigned short*)uni;            // 2048 us
    unsigned short* aL = (unsigned short*)uni + 2048;     // 2048 us
    unsigned short* lH = (unsigned short*)uni;            // 4096 us (after reuse)
    unsigned short* lL = (unsigned short*)uni + 4096;     // 4096 us
    float* sTri = (float*)sY;                             // 2176-float overlay
    int t = threadIdx.x;                          // 256 threads, 4 waves
    int lane = t & 63, wave = t >> 6;
    int e0 = blockIdx.x * FGK_EPB;

    if (t < FGK_EPB) {
        int e = perm[e0 + t];
        sE[t] = e;
        sSrc[t] = srcIdx[e];
        sDst[t] = dstIdx[e];
    }
    __syncthreads();

    // ---- bulk-parallel prefetch of the 16 hin rows (8 independent loads/thread) ----
#pragma unroll
    for (int i = 0; i < 8; ++i) {
        int o = t + i * 256;
        int el = o >> 7, k = o & 127;
        sY[el][k] = hin[(size_t)sSrc[el] * FGK_H + k];
    }
    if (t == 0) {                                 // slot runs over sorted dsts
        int ns = 0;
        for (int el = 0; el < FGK_EPB; ++el) {
            if (el == 0 || sDst[el] != sDst[el - 1]) {
                if (ns) sEnd[ns - 1] = el;
                sStart[ns] = el;
                sDstSlot[ns] = sDst[el];
                ++ns;
            }
        }
        sEnd[ns - 1] = FGK_EPB;
        sNS = ns;
    }
    __syncthreads();

    // ---- msg = relu(hin + ea) + 1e-7 -> bf16 hi/lo A-frags (reads LDS rows) ----
#pragma unroll
    for (int i = 0; i < 8; ++i) {
        int o = t + i * 256;
        int el = o >> 7, k = o & 127;
        float acc = eeb[k];
        const float* ep = eatt + (size_t)sE[el] * 8;
#pragma unroll
        for (int kk = 0; kk < 8; kk++) acc += ep[kk] * eew[kk * FGK_H + k];
        float m = sY[el][k] + acc;
        m = fmaxf(m, 0.f) + 1e-7f;
        unsigned short hb = fgk_f2b(m);
        unsigned short lb = fgk_f2b(m - fgk_u2f(hb));
        int c = k >> 5, g = (k >> 3) & 3, jj = k & 7;
        int idx = (c * 64 + el + 16 * g) * 8 + jj;
        aH[idx] = hb; aL[idx] = lb;
    }
    __syncthreads();

    // ---- y = msg @ a1w via MFMA (overwrites sY with y) ----
    {
        s16x8 ah[4], al[4];
#pragma unroll
        for (int c = 0; c < 4; ++c) {
            ah[c] = *(const s16x8*)&aH[(c * 64 + lane) * 8];
            al[c] = *(const s16x8*)&aL[(c * 64 + lane) * 8];
        }
        int n = lane & 15, qd = lane >> 4;
        for (int nt = wave; nt < 10; nt += 4) {
            f32x4 acc = {0.f, 0.f, 0.f, 0.f};
#pragma unroll
            for (int c = 0; c < 4; ++c) {
                size_t bidx = ((size_t)(nt * 4 + c) * 64 + lane) * 8;
                s16x8 bh = *(const s16x8*)(bHi + bidx);
                s16x8 bl = *(const s16x8*)(bLo + bidx);
                acc = __builtin_amdgcn_mfma_f32_16x16x32_bf16(al[c], bh, acc, 0, 0, 0);
                acc = __builtin_amdgcn_mfma_f32_16x16x32_bf16(ah[c], bl, acc, 0, 0, 0);
                acc = __builtin_amdgcn_mfma_f32_16x16x32_bf16(ah[c], bh, acc, 0, 0, 0);
            }
            int j = nt * 16 + n;
            if (j < FGK_F) {                       // GUARD: pad columns (152..159) must
                float bias = a1b[j];               // NOT wrap into the next sY row
#pragma unroll
                for (int reg = 0; reg < 4; ++reg)
                    sY[4 * qd + reg][j] = acc[reg] + bias;   // C/D: col=lane&15, row=4*qd+reg
            }
        }
    }
    __syncthreads();   // sY = y; aH/aL dead -> uni becomes L-frag region

    // ---- L build pass 1: all entries, no softplus ----
#pragma unroll
    for (int it = 0; it < FGK_EPB; ++it) {
        int o = t + it * 256;
        int el = o >> 8, p = o & 255;
        int q = (p < 120) ? (p + 16) : (255 - p);   // FILL_IDX[p]
        float v = sY[el][16 + q];
        int i = p >> 4, j = p & 15;
        unsigned short hb = fgk_f2b(v);
        unsigned short lb = fgk_f2b(v - fgk_u2f(hb));
        int lanep = i + ((j >> 3) << 4);            // frag lane (0..31)
        int idx = el * 256 + lanep * 8 + (j & 7);
        lH[idx] = hb; lL[idx] = lb;
    }
    __syncthreads();

    // ---- pass 2: diag softplus + per-slot score reduction/atomics ----
    {
        int el = t >> 4, d = t & 15;
        int p = 17 * d;
        int q = (p < 120) ? (p + 16) : (255 - p);
        float v = sY[el][16 + q];
        v = fmaxf(v, 0.f) + log1pf(expf(-fabsf(v)));  // softplus
        unsigned short hb = fgk_f2b(v);
        unsigned short lb = fgk_f2b(v - fgk_u2f(hb));
        int lanep = d + ((d >> 3) << 4);
        int idx = el * 256 + lanep * 8 + (d & 7);
        lH[idx] = hb; lL[idx] = lb;
        int s = el, j = d;
        if (s < sNS) {
            float sum = 0.f;
            for (int e2 = sStart[s]; e2 < sEnd[s]; ++e2) sum += sY[e2][j];
            atomicAdd(&snAcc[(size_t)sDstSlot[s] * FGK_P + j], sum);
        }
    }
    __syncthreads();

    // ---- Fe = L L^T via MFMA; park lower tri in LDS (overlay sY) ----
#pragma unroll
    for (int i4 = 0; i4 < 4; ++i4) {
        int el = wave * 4 + i4;
        s16x8 fh = {0, 0, 0, 0, 0, 0, 0, 0};
        s16x8 fl = {0, 0, 0, 0, 0, 0, 0, 0};
        if (lane < 32) {
            fh = *(const s16x8*)&lH[el * 256 + lane * 8];
            fl = *(const s16x8*)&lL[el * 256 + lane * 8];
        }
        f32x4 acc = {0.f, 0.f, 0.f, 0.f};
        acc = __builtin_amdgcn_mfma_f32_16x16x32_bf16(fh, fh, acc, 0, 0, 0);
        acc = __builtin_amdgcn_mfma_f32_16x16x32_bf16(fh, fl, acc, 0, 0, 0);
        acc = __builtin_amdgcn_mfma_f32_16x16x32_bf16(fl, fh, acc, 0, 0, 0);
        int j = lane & 15, qd = lane >> 4;
#pragma unroll
        for (int reg = 0; reg < 4; ++reg) {
            int ii = 4 * qd + reg;
            if (ii >= j) sTri[el * FGK_TRI + ii * (ii + 1) / 2 + j] = acc[reg];
        }
    }
    __syncthreads();

    // ---- per-slot tri reduction -> coalesced atomics ----
    {
        int nS = sNS;
        for (int o = t; o < nS * FGK_TRI; o += 256) {
            int s = o / FGK_TRI, p = o - s * FGK_TRI;
            float sum = 0.f;
            for (int el = sStart[s]; el < sEnd[s]; ++el) sum += sTri[el * FGK_TRI + p];
            atomicAdd(&fnAcc[(size_t)sDstSlot[s] * FGK_TRI + p], sum);
        }
    }
}

// one thread per node: fully-unrolled register Cholesky solve of (F_n+I) x = s_n
#define TA(i, j) a[(i) * ((i) + 1) / 2 + (j)]
__global__ void __launch_bounds__(256)
fgkSolve(const float* __restrict__ snAcc,
         const float* __restrict__ fnAcc,
         float* __restrict__ mleOut)
{
    int n = blockIdx.x * blockDim.x + threadIdx.x;
    if (n >= FGK_NN) return;
    float a[FGK_TRI];
    const float4* src = (const float4*)(fnAcc + (size_t)n * FGK_TRI);
#pragma unroll
    for (int p = 0; p < FGK_TRI / 4; ++p) {
        float4 v = src[p];
        a[p * 4] = v.x; a[p * 4 + 1] = v.y; a[p * 4 + 2] = v.z; a[p * 4 + 3] = v.w;
    }
#pragma unroll
    for (int i = 0; i < 16; ++i) TA(i, i) += 1.f;
#pragma unroll
    for (int k = 0; k < 16; ++k) {
        float d = sqrtf(TA(k, k));
        float inv = 1.f / d;
        TA(k, k) = d;
#pragma unroll
        for (int i = k + 1; i < 16; ++i) TA(i, k) *= inv;
#pragma unroll
        for (int j = k + 1; j < 16; ++j) {
            float ajk = TA(j, k);
#pragma unroll
            for (int i = j; i < 16; ++i) TA(i, j) -= TA(i, k) * ajk;
        }
    }
    const float* sp = snAcc + (size_t)n * FGK_P;
    float y[16], x[16];
#pragma unroll
    for (int i = 0; i < 16; ++i) {
        float acc = sp[i];
#pragma unroll
        for (int k = 0; k < 16; ++k) if (k < i) acc -= TA(i, k) * y[k];
        y[i] = acc / TA(i, i);
    }
#pragma unroll
    for (int i = 15; i >= 0; --i) {
        float acc = y[i];
#pragma unroll
        for (int k = 0; k < 16; ++k) if (k > i) acc -= TA(k, i) * x[k];
        x[i] = acc / TA(i, i);
    }
    float4* dst = (float4*)(mleOut + (size_t)n * FGK_P);
#pragma unroll
    for (int p = 0; p < 4; ++p) dst[p] = make_float4(x[p * 4], x[p * 4 + 1], x[p * 4 + 2], x[p * 4 + 3]);
}
#undef TA

// node (16 nodes/block): a2+res -> m1 MFMA -> LN -> m2 MFMA -> hout
__global__ void __launch_bounds__(256)
fgkNode(const float* __restrict__ hin,
        const float* __restrict__ mleIn,
        const float* __restrict__ a2w, const float* __restrict__ a2b,
        const unsigned short* __restrict__ m1H, const unsigned short* __restrict__ m1L,
        const float* __restrict__ m1b,
        const float* __restrict__ gamma, const float* __restrict__ beta,
        const unsigned short* __restrict__ m2H, const unsigned short* __restrict__ m2L,
        const float* __restrict__ m2b,
        float* __restrict__ hout, int addres)
{
    __shared__ char uniN[16384];
    __shared__ float sT[16][260];
    __shared__ float stats[16][2];
    unsigned short* ovH = (unsigned short*)uniN;
    unsigned short* ovL = (unsigned short*)uniN + 2048;
    unsigned short* t2H = (unsigned short*)uniN;
    unsigned short* t2L = (unsigned short*)uniN + 4096;
    int t = threadIdx.x, lane = t & 63, wave = t >> 6;
    int n0 = blockIdx.x * 16;

#pragma unroll
    for (int pass = 0; pass < 8; ++pass) {
        int node = pass * 2 + (t >> 7);
        int col = t & 127;
        const float* mp = mleIn + (size_t)(n0 + node) * FGK_P;
        float acc = a2b[col];
#pragma unroll
        for (int k = 0; k < 16; ++k) acc += mp[k] * a2w[k * FGK_H + col];
        acc += hin[(size_t)(n0 + node) * FGK_H + col];
        unsigned short hb = fgk_f2b(acc);
        unsigned short lb = fgk_f2b(acc - fgk_u2f(hb));
        int c = col >> 5, g = (col >> 3) & 3, jj = col & 7;
        int idx = (c * 64 + node + 16 * g) * 8 + jj;
        ovH[idx] = hb; ovL[idx] = lb;
    }
    __syncthreads();

    {
        s16x8 ah[4], al[4];
#pragma unroll
        for (int c = 0; c < 4; ++c) {
            ah[c] = *(const s16x8*)&ovH[(c * 64 + lane) * 8];
            al[c] = *(const s16x8*)&ovL[(c * 64 + lane) * 8];
        }
        int n = lane & 15, qd = lane >> 4;
#pragma unroll
        for (int i4 = 0; i4 < 4; ++i4) {
            int nt = wave + i4 * 4;
            f32x4 acc = {0.f, 0.f, 0.f, 0.f};
#pragma unroll
            for (int c = 0; c < 4; ++c) {
                size_t bidx = ((size_t)(nt * 4 + c) * 64 + lane) * 8;
                s16x8 bh = *(const s16x8*)(m1H + bidx);
                s16x8 bl = *(const s16x8*)(m1L + bidx);
                acc = __builtin_amdgcn_mfma_f32_16x16x32_bf16(al[c], bh, acc, 0, 0, 0);
                acc = __builtin_amdgcn_mfma_f32_16x16x32_bf16(ah[c], bl, acc, 0, 0, 0);
                acc = __builtin_amdgcn_mfma_f32_16x16x32_bf16(ah[c], bh, acc, 0, 0, 0);
            }
            int j = nt * 16 + n;
            float bias = m1b[j];
#pragma unroll
            for (int reg = 0; reg < 4; ++reg)
                sT[4 * qd + reg][j] = acc[reg] + bias;
        }
    }
    __syncthreads();

    {
        int node = t >> 4, seg = t & 15;
        const float* rowp = &sT[node][seg * 16];
        float s1 = 0.f, s2 = 0.f;
#pragma unroll
        for (int k = 0; k < 16; ++k) { float v = rowp[k]; s1 += v; s2 += v * v; }
#pragma unroll
        for (int off = 8; off; off >>= 1) {
            s1 += __shfl_down(s1, off, 16);
            s2 += __shfl_down(s2, off, 16);
        }
        if (seg == 0) {
            float mu = s1 * (1.f / 256.f);
            float var = s2 * (1.f / 256.f) - mu * mu;
            stats[node][0] = mu;
            stats[node][1] = rsqrtf(var + 1e-5f);
        }
    }
    __syncthreads();

    {
        int node = t >> 4, seg = t & 15;
        float mu = stats[node][0], rstd = stats[node][1];
#pragma unroll
        for (int kk = 0; kk < 16; ++kk) {
            int k = seg * 16 + kk;
            float v = sT[node][k];
            float tv = fmaxf((v - mu) * rstd * gamma[k] + beta[k], 0.f);
            unsigned short hb = fgk_f2b(tv);
            unsigned short lb = fgk_f2b(tv - fgk_u2f(hb));
            int c = k >> 5, g = (k >> 3) & 3, jj = k & 7;
            int idx = (c * 64 + node + 16 * g) * 8 + jj;
            t2H[idx] = hb; t2L[idx] = lb;
        }
    }
    __syncthreads();

    {
        s16x8 ah[8], al[8];
#pragma unroll
        for (int c = 0; c < 8; ++c) {
            ah[c] = *(const s16x8*)&t2H[(c * 64 + lane) * 8];
            al[c] = *(const s16x8*)&t2L[(c * 64 + lane) * 8];
        }
        int n = lane & 15, qd = lane >> 4;
#pragma unroll
        for (int i2 = 0; i2 < 2; ++i2) {
            int nt = wave * 2 + i2;
            f32x4 acc = {0.f, 0.f, 0.f, 0.f};
#pragma unroll
            for (int c = 0; c < 8; ++c) {
                size_t bidx = ((size_t)(nt * 8 + c) * 64 + lane) * 8;
                s16x8 bh = *(const s16x8*)(m2H + bidx);
                s16x8 bl = *(const s16x8*)(m2L + bidx);
                acc = __builtin_amdgcn_mfma_f32_16x16x32_bf16(al[c], bh, acc, 0, 0, 0);
                acc = __builtin_amdgcn_mfma_f32_16x16x32_bf16(ah[c], bl, acc, 0, 0, 0);
                acc = __builtin_amdgcn_mfma_f32_16x16x32_bf16(ah[c], bh, acc, 0, 0, 0);
            }
            int j = nt * 16 + n;
            float bias = m2b[j];
#pragma unroll
            for (int reg = 0; reg < 4; ++reg) {
                int node = 4 * qd + reg;
                size_t idx = (size_t)(n0 + node) * FGK_H + j;
                float val = acc[reg] + bias;
                hout[idx] = addres ? (hout[idx] + val) : val;
            }
        }
    }
}

// out = relu(LN(h, g0, b0)) @ lin_w + lin_b   (f32 out)
__global__ void fgkFinal(const float* __restrict__ hsrc,
                         const float* __restrict__ gamma,
                         const float* __restrict__ beta,
                         const float* __restrict__ lw,
                         const float* __restrict__ lb,
                         float* __restrict__ outp)
{
    int n = blockIdx.x, t = threadIdx.x;   // block = 128
    __shared__ float tt[FGK_H];
    __shared__ float red[4];
    float v = hsrc[(size_t)n * FGK_H + t];
    float s1 = v, s2 = v * v;
#pragma unroll
    for (int off = 32; off; off >>= 1) { s1 += __shfl_down(s1, off); s2 += __shfl_down(s2, off); }
    int wid = t >> 6, lane = t & 63;
    if (lane == 0) { red[wid] = s1; red[2 + wid] = s2; }
    __syncthreads();
    float mu = (red[0] + red[1]) * (1.f / FGK_H);
    float var = (red[2] + red[3]) * (1.f / FGK_H) - mu * mu;
    float rstd = rsqrtf(var + 1e-5f);
    tt[t] = fmaxf((v - mu) * rstd * gamma[t] + beta[t], 0.f);
    __syncthreads();
    if (t < 112) {
        float acc = lb[t];
        for (int k = 0; k < FGK_H; k++) acc += tt[k] * lw[k * 112 + t];
        outp[(size_t)n * 112 + t] = acc;
    }
}

extern "C" void kernel_launch(void* const* d_in, const int* in_sizes, int n_in,
                              void* d_out, int out_size, void* d_ws, size_t ws_size,
                              hipStream_t stream)
{
    const float* xin  = (const float*)d_in[0];
    const float* eatt = (const float*)d_in[1];
    const int*   eidx = (const int*)d_in[2];
    const float* nEw  = (const float*)d_in[3];
    const float* nEb  = (const float*)d_in[4];
    const float* eEw  = (const float*)d_in[5];
    const float* eEb  = (const float*)d_in[6];
    const float* a1w  = (const float*)d_in[7];
    const float* a1b  = (const float*)d_in[8];
    const float* a2w  = (const float*)d_in[9];
    const float* a2b  = (const float*)d_in[10];
    const float* m1w  = (const float*)d_in[11];
    const float* m1b  = (const float*)d_in[12];
    const float* lng  = (const float*)d_in[13];
    const float* lnb  = (const float*)d_in[14];
    const float* m2w  = (const float*)d_in[15];
    const float* m2b  = (const float*)d_in[16];
    const float* ng   = (const float*)d_in[17];
    const float* nb   = (const float*)d_in[18];
    const float* lw   = (const float*)d_in[19];
    const float* lb   = (const float*)d_in[20];
    float* outp = (float*)d_out;
    const int* srcIdx = eidx;
    const int* dstIdx = eidx + FGK_NE;

    float* ws   = (float*)d_ws;
    float* hAcc = ws;                                    // NN*128
    float* hin  = hAcc + (size_t)FGK_NN * FGK_H;         // NN*128
    float* snA  = hin  + (size_t)FGK_NN * FGK_H;         // NN*16
    float* fnA  = snA  + (size_t)FGK_NN * FGK_P;         // NN*136
    float* mle  = fnA  + (size_t)FGK_NN * FGK_TRI;       // NN*16
    unsigned short* wsU = (unsigned short*)(mle + (size_t)FGK_NN * FGK_P);
    const int A1F = 40 * 512, M1F = 64 * 512, M2F = 64 * 512;
    unsigned short* a1Hi = wsU;
    unsigned short* a1Lo = a1Hi + 3 * A1F;
    unsigned short* m1Hi = a1Lo + 3 * A1F;
    unsigned short* m1Lo = m1Hi + 3 * M1F;
    unsigned short* m2Hi = m1Lo + 3 * M1F;
    unsigned short* m2Lo = m2Hi + 3 * M2F;
    int* cursor = (int*)(m2Lo + 3 * M2F);                // NN ints
    int* perm   = cursor + FGK_NN;                       // NE ints

    // dst-sorted edge permutation (edge_index constant; rebuilt every launch)
    fgkZeroI<<<(FGK_NN + 255) / 256, 256, 0, stream>>>(cursor, FGK_NN);
    fgkHist<<<(FGK_NE + 255) / 256, 256, 0, stream>>>(dstIdx, cursor);
    fgkScan<<<1, 1024, 0, stream>>>(cursor, cursor);     // in-place exclusive scan
    fgkScatterE<<<(FGK_NE + 255) / 256, 256, 0, stream>>>(dstIdx, cursor, perm);

    for (int l = 0; l < 3; l++) {
        fgkPrepW<<<40, 64, 0, stream>>>(a1w + (size_t)l * FGK_H * FGK_F, 128, 152,
                                        a1Hi + l * A1F, a1Lo + l * A1F);
        fgkPrepW<<<64, 64, 0, stream>>>(m1w + (size_t)l * FGK_H * 256, 128, 256,
                                        m1Hi + l * M1F, m1Lo + l * M1F);
        fgkPrepW<<<64, 64, 0, stream>>>(m2w + (size_t)l * 256 * FGK_H, 256, 128,
                                        m2Hi + l * M2F, m2Lo + l * M2F);
    }
    fgkEnc<<<(FGK_NN * FGK_H + 255) / 256, 256, 0, stream>>>(xin, nEw, nEb, hin);
    for (int l = 0; l < 3; l++) {
        if (l > 0)
            fgkLn<<<FGK_NN, FGK_H, 0, stream>>>(hAcc, ng + l * FGK_H, nb + l * FGK_H, hin);
        fgkZero<<<(FGK_NN * (FGK_P + FGK_TRI) + 255) / 256, 256, 0, stream>>>(snA);
        fgkEdge<<<FGK_NE / FGK_EPB, 256, 0, stream>>>(eatt, srcIdx, dstIdx, perm, eEw, eEb,
            a1Hi + l * A1F, a1Lo + l * A1F, a1b + (size_t)l * FGK_F, hin, snA, fnA);
        fgkSolve<<<(FGK_NN + 255) / 256, 256, 0, stream>>>(snA, fnA, mle);
        fgkNode<<<FGK_NN / 16, 256, 0, stream>>>(hin, mle,
            a2w + (size_t)l * FGK_P * FGK_H, a2b + (size_t)l * FGK_H,
            m1Hi + l * M1F, m1Lo + l * M1F, m1b + (size_t)l * 256,
            lng + (size_t)l * 256, lnb + (size_t)l * 256,
            m2Hi + l * M2F, m2Lo + l * M2F, m2b + (size_t)l * FGK_H,
            hAcc, l > 0 ? 1 : 0);
    }
    fgkFinal<<<FGK_NN, FGK_H, 0, stream>>>(hAcc, ng, nb, lw, lb, outp);
}

// Round 16
// 944.751 us; speedup vs baseline: 1.0452x; 1.0452x over previous
//
#include <hip/hip_runtime.h>
#include <cmath>
#include <cstddef>

#define FGK_NN   20000
#define FGK_NE   320000
#define FGK_H    128
#define FGK_P    16
#define FGK_TRI  136
#define FGK_F    152
#define FGK_EPB  16
#define FGK_YP   153          // sY row stride (>=152)

typedef short  s16x8 __attribute__((ext_vector_type(8)));
typedef float  f32x4 __attribute__((ext_vector_type(4)));

__device__ __forceinline__ unsigned short fgk_f2b(float f) {   // RNE f32->bf16 bits
    unsigned int u = __float_as_uint(f);
    return (unsigned short)((u + 0x7FFFu + ((u >> 16) & 1u)) >> 16);
}
__device__ __forceinline__ float fgk_u2f(unsigned short u) {
    return __uint_as_float(((unsigned int)u) << 16);
}

__global__ void FishnetGCN_62096637165586_kernel() {}

__global__ void fgkZero(float* acc) {
    int i = blockIdx.x * blockDim.x + threadIdx.x;
    if (i < FGK_NN * (FGK_P + FGK_TRI)) acc[i] = 0.f;
}
__global__ void fgkZeroI(int* p, int n) {
    int i = blockIdx.x * blockDim.x + threadIdx.x;
    if (i < n) p[i] = 0;
}
// ---- dst-sort: histogram -> block scan -> scatter (edge_index constant) ----
__global__ void fgkHist(const int* __restrict__ dst, int* __restrict__ hist) {
    int e = blockIdx.x * blockDim.x + threadIdx.x;
    if (e < FGK_NE) atomicAdd(&hist[dst[e]], 1);
}
__global__ void fgkScan(const int* __restrict__ hist, int* __restrict__ cursor)
{
    __shared__ int sWave[16];
    __shared__ int sRun;
    int t = threadIdx.x;             // 1024
    int lane = t & 63, wv = t >> 6;
    if (t == 0) sRun = 0;
    __syncthreads();
    for (int base = 0; base < FGK_NN; base += 1024) {
        int idx = base + t;
        int v = (idx < FGK_NN) ? hist[idx] : 0;
        int sc = v;
#pragma unroll
        for (int off = 1; off < 64; off <<= 1) {
            int u = __shfl_up(sc, off);
            if (lane >= off) sc += u;
        }
        if (lane == 63) sWave[wv] = sc;
        __syncthreads();
        if (wv == 0 && lane < 16) {
            int w = sWave[lane];
#pragma unroll
            for (int off = 1; off < 16; off <<= 1) {
                int u = __shfl_up(w, off, 16);
                if (lane >= off) w += u;
            }
            sWave[lane] = w;
        }
        __syncthreads();
        int waveOff = (wv == 0) ? 0 : sWave[wv - 1];
        int run = sRun;
        if (idx < FGK_NN) cursor[idx] = run + waveOff + sc - v;   // exclusive
        __syncthreads();
        if (t == 1023) sRun = run + sWave[15];
        __syncthreads();
    }
}
__global__ void fgkScatterE(const int* __restrict__ dst, int* __restrict__ cursor,
                            int* __restrict__ perm) {
    int e = blockIdx.x * blockDim.x + threadIdx.x;
    if (e < FGK_NE) {
        int pos = atomicAdd(&cursor[dst[e]], 1);
        perm[pos] = e;
    }
}

// Generic prepack of W[K,N] (row-major) into MFMA B-fragment order, bf16 hi/lo.
__global__ void fgkPrepW(const float* __restrict__ W, int K, int N,
                         unsigned short* __restrict__ hi,
                         unsigned short* __restrict__ lo)
{
    int chunks = K >> 5;
    int b = blockIdx.x;
    int nt = b / chunks, c = b - nt * chunks;
    int lane = threadIdx.x;
    int n = nt * 16 + (lane & 15);
    int g = lane >> 4;
    size_t base = ((size_t)b * 64 + lane) * 8;
#pragma unroll
    for (int j = 0; j < 8; ++j) {
        int k = c * 32 + g * 8 + j;
        float v = (n < N) ? W[(size_t)k * N + n] : 0.f;
        unsigned short hb = fgk_f2b(v);
        unsigned short lb = fgk_f2b(v - fgk_u2f(hb));
        hi[base + j] = hb;
        lo[base + j] = lb;
    }
}

// hin = x @ W[8,128] + b
__global__ void fgkEnc(const float* __restrict__ xin,
                       const float* __restrict__ wenc,
                       const float* __restrict__ benc,
                       float* __restrict__ hin)
{
    int idx = blockIdx.x * blockDim.x + threadIdx.x;
    if (idx >= FGK_NN * FGK_H) return;
    int n = idx >> 7, j = idx & 127;
    float acc = benc[j];
    const float* xp = xin + (size_t)n * 8;
#pragma unroll
    for (int k = 0; k < 8; k++) acc += xp[k] * wenc[k * FGK_H + j];
    hin[idx] = acc;
}

// edge (sorted by dst): direct-load msg -> frags ; y=MFMA ; L->frags ;
// Fe=MFMA ; per-slot LDS reduction ; ~152 atomics per distinct dst
__global__ void __launch_bounds__(256)
fgkEdge(const float* __restrict__ eatt,
        const int* __restrict__ srcIdx,
        const int* __restrict__ dstIdx,
        const int* __restrict__ perm,
        const float* __restrict__ eew,
        const float* __restrict__ eeb,
        const unsigned short* __restrict__ bHi,
        const unsigned short* __restrict__ bLo,
        const float* __restrict__ a1b,
        const float* __restrict__ hin,
        float* __restrict__ snAcc,
        float* __restrict__ fnAcc)
{
    __shared__ float uni[4096];                   // 16 KB: A-frags, then L-frags
    __shared__ float sY[FGK_EPB][FGK_YP];         // y, later overlaid by sTri
    __shared__ int sE[FGK_EPB], sSrc[FGK_EPB], sDst[FGK_EPB];
    __shared__ int sStart[FGK_EPB], sEnd[FGK_EPB], sDstSlot[FGK_EPB];
    __shared__ int sNS;
    unsigned short* aH = (unsigned short*)uni;            // 2048 us
    unsigned short* aL = (unsigned short*)uni + 2048;     // 2048 us
    unsigned short* lH = (unsigned short*)uni;            // 4096 us (after reuse)
    unsigned short* lL = (unsigned short*)uni + 4096;     // 4096 us
    float* sTri = (float*)sY;                             // 2176-float overlay
    int t = threadIdx.x;                          // 256 threads, 4 waves
    int lane = t & 63, wave = t >> 6;
    int e0 = blockIdx.x * FGK_EPB;

    if (t < FGK_EPB) {
        int e = perm[e0 + t];
        sE[t] = e;
        sSrc[t] = srcIdx[e];
        sDst[t] = dstIdx[e];
    }
    __syncthreads();
    if (t == 0) {                                 // slot runs over sorted dsts
        int ns = 0;
        for (int el = 0; el < FGK_EPB; ++el) {
            if (el == 0 || sDst[el] != sDst[el - 1]) {
                if (ns) sEnd[ns - 1] = el;
                sStart[ns] = el;
                sDstSlot[ns] = sDst[el];
                ++ns;
            }
        }
        sEnd[ns - 1] = FGK_EPB;
        sNS = ns;
    }

    // ---- msg = relu(hin[src] + ea) + 1e-7 -> bf16 hi/lo A-frags ----
    // one thread <-> (edge el, 8 consecutive cols); all inputs via float4
    {
        int el = t >> 4, b = t & 15;
        const float4* hp = (const float4*)(hin + (size_t)sSrc[el] * FGK_H + b * 8);
        float4 h0 = hp[0], h1 = hp[1];
        const float4* ap = (const float4*)(eatt + (size_t)sE[el] * 8);
        float4 a0 = ap[0], a1 = ap[1];
        float av[8] = {a0.x, a0.y, a0.z, a0.w, a1.x, a1.y, a1.z, a1.w};
        const float4* bp = (const float4*)(eeb + b * 8);
        float4 b0 = bp[0], b1 = bp[1];
        float acc[8] = {b0.x, b0.y, b0.z, b0.w, b1.x, b1.y, b1.z, b1.w};
#pragma unroll
        for (int kk = 0; kk < 8; ++kk) {
            const float4* wp = (const float4*)(eew + kk * FGK_H + b * 8);
            float4 w0 = wp[0], w1 = wp[1];
            acc[0] += av[kk] * w0.x; acc[1] += av[kk] * w0.y;
            acc[2] += av[kk] * w0.z; acc[3] += av[kk] * w0.w;
            acc[4] += av[kk] * w1.x; acc[5] += av[kk] * w1.y;
            acc[6] += av[kk] * w1.z; acc[7] += av[kk] * w1.w;
        }
        float hv[8] = {h0.x, h0.y, h0.z, h0.w, h1.x, h1.y, h1.z, h1.w};
        s16x8 hb, lb;
#pragma unroll
        for (int jj = 0; jj < 8; ++jj) {
            float m = fmaxf(hv[jj] + acc[jj], 0.f) + 1e-7f;
            unsigned short h = fgk_f2b(m);
            hb[jj] = (short)h;
            lb[jj] = (short)fgk_f2b(m - fgk_u2f(h));
        }
        int c = b >> 2, g = b & 3;                // k = b*8+jj = 32c+8g+jj
        int idx = (c * 64 + el + 16 * g) * 8;
        *(s16x8*)&aH[idx] = hb;
        *(s16x8*)&aL[idx] = lb;
    }
    __syncthreads();

    // ---- y = msg @ a1w via MFMA (writes sY) ----
    {
        s16x8 ah[4], al[4];
#pragma unroll
        for (int c = 0; c < 4; ++c) {
            ah[c] = *(const s16x8*)&aH[(c * 64 + lane) * 8];
            al[c] = *(const s16x8*)&aL[(c * 64 + lane) * 8];
        }
        int n = lane & 15, qd = lane >> 4;
        for (int nt = wave; nt < 10; nt += 4) {
            f32x4 acc = {0.f, 0.f, 0.f, 0.f};
#pragma unroll
            for (int c = 0; c < 4; ++c) {
                size_t bidx = ((size_t)(nt * 4 + c) * 64 + lane) * 8;
                s16x8 bh = *(const s16x8*)(bHi + bidx);
                s16x8 bl = *(const s16x8*)(bLo + bidx);
                acc = __builtin_amdgcn_mfma_f32_16x16x32_bf16(al[c], bh, acc, 0, 0, 0);
                acc = __builtin_amdgcn_mfma_f32_16x16x32_bf16(ah[c], bl, acc, 0, 0, 0);
                acc = __builtin_amdgcn_mfma_f32_16x16x32_bf16(ah[c], bh, acc, 0, 0, 0);
            }
            int j = nt * 16 + n;
            if (j < FGK_F) {                       // GUARD: pad cols must not wrap
                float bias = a1b[j];
#pragma unroll
                for (int reg = 0; reg < 4; ++reg)
                    sY[4 * qd + reg][j] = acc[reg] + bias;   // C/D: col=lane&15, row=4*qd+reg
            }
        }
    }
    __syncthreads();   // sY = y; aH/aL dead -> uni becomes L-frag region

    // ---- L build pass 1: all entries, no softplus ----
#pragma unroll
    for (int it = 0; it < FGK_EPB; ++it) {
        int o = t + it * 256;
        int el = o >> 8, p = o & 255;
        int q = (p < 120) ? (p + 16) : (255 - p);   // FILL_IDX[p]
        float v = sY[el][16 + q];
        int i = p >> 4, j = p & 15;
        unsigned short hb = fgk_f2b(v);
        unsigned short lb = fgk_f2b(v - fgk_u2f(hb));
        int lanep = i + ((j >> 3) << 4);            // frag lane (0..31)
        int idx = el * 256 + lanep * 8 + (j & 7);
        lH[idx] = hb; lL[idx] = lb;
    }
    __syncthreads();

    // ---- pass 2: diag softplus + per-slot score reduction/atomics ----
    {
        int el = t >> 4, d = t & 15;
        int p = 17 * d;
        int q = (p < 120) ? (p + 16) : (255 - p);
        float v = sY[el][16 + q];
        v = fmaxf(v, 0.f) + log1pf(expf(-fabsf(v)));  // softplus
        unsigned short hb = fgk_f2b(v);
        unsigned short lb = fgk_f2b(v - fgk_u2f(hb));
        int lanep = d + ((d >> 3) << 4);
        int idx = el * 256 + lanep * 8 + (d & 7);
        lH[idx] = hb; lL[idx] = lb;
        int s = el, j = d;
        if (s < sNS) {
            float sum = 0.f;
            for (int e2 = sStart[s]; e2 < sEnd[s]; ++e2) sum += sY[e2][j];
            atomicAdd(&snAcc[(size_t)sDstSlot[s] * FGK_P + j], sum);
        }
    }
    __syncthreads();

    // ---- Fe = L L^T via MFMA; park lower tri in LDS (overlay sY) ----
#pragma unroll
    for (int i4 = 0; i4 < 4; ++i4) {
        int el = wave * 4 + i4;
        s16x8 fh = {0, 0, 0, 0, 0, 0, 0, 0};
        s16x8 fl = {0, 0, 0, 0, 0, 0, 0, 0};
        if (lane < 32) {
            fh = *(const s16x8*)&lH[el * 256 + lane * 8];
            fl = *(const s16x8*)&lL[el * 256 + lane * 8];
        }
        f32x4 acc = {0.f, 0.f, 0.f, 0.f};
        acc = __builtin_amdgcn_mfma_f32_16x16x32_bf16(fh, fh, acc, 0, 0, 0);
        acc = __builtin_amdgcn_mfma_f32_16x16x32_bf16(fh, fl, acc, 0, 0, 0);
        acc = __builtin_amdgcn_mfma_f32_16x16x32_bf16(fl, fh, acc, 0, 0, 0);
        int j = lane & 15, qd = lane >> 4;
#pragma unroll
        for (int reg = 0; reg < 4; ++reg) {
            int ii = 4 * qd + reg;
            if (ii >= j) sTri[el * FGK_TRI + ii * (ii + 1) / 2 + j] = acc[reg];
        }
    }
    __syncthreads();

    // ---- per-slot tri reduction -> coalesced atomics ----
    {
        int nS = sNS;
        for (int o = t; o < nS * FGK_TRI; o += 256) {
            int s = o / FGK_TRI, p = o - s * FGK_TRI;
            float sum = 0.f;
            for (int el = sStart[s]; el < sEnd[s]; ++el) sum += sTri[el * FGK_TRI + p];
            atomicAdd(&fnAcc[(size_t)sDstSlot[s] * FGK_TRI + p], sum);
        }
    }
}

// one thread per node: fully-unrolled register Cholesky solve of (F_n+I) x = s_n
#define TA(i, j) a[(i) * ((i) + 1) / 2 + (j)]
__global__ void __launch_bounds__(256)
fgkSolve(const float* __restrict__ snAcc,
         const float* __restrict__ fnAcc,
         float* __restrict__ mleOut)
{
    int n = blockIdx.x * blockDim.x + threadIdx.x;
    if (n >= FGK_NN) return;
    float a[FGK_TRI];
    const float4* src = (const float4*)(fnAcc + (size_t)n * FGK_TRI);
#pragma unroll
    for (int p = 0; p < FGK_TRI / 4; ++p) {
        float4 v = src[p];
        a[p * 4] = v.x; a[p * 4 + 1] = v.y; a[p * 4 + 2] = v.z; a[p * 4 + 3] = v.w;
    }
#pragma unroll
    for (int i = 0; i < 16; ++i) TA(i, i) += 1.f;
#pragma unroll
    for (int k = 0; k < 16; ++k) {
        float d = sqrtf(TA(k, k));
        float inv = 1.f / d;
        TA(k, k) = d;
#pragma unroll
        for (int i = k + 1; i < 16; ++i) TA(i, k) *= inv;
#pragma unroll
        for (int j = k + 1; j < 16; ++j) {
            float ajk = TA(j, k);
#pragma unroll
            for (int i = j; i < 16; ++i) TA(i, j) -= TA(i, k) * ajk;
        }
    }
    const float* sp = snAcc + (size_t)n * FGK_P;
    float y[16], x[16];
#pragma unroll
    for (int i = 0; i < 16; ++i) {
        float acc = sp[i];
#pragma unroll
        for (int k = 0; k < 16; ++k) if (k < i) acc -= TA(i, k) * y[k];
        y[i] = acc / TA(i, i);
    }
#pragma unroll
    for (int i = 15; i >= 0; --i) {
        float acc = y[i];
#pragma unroll
        for (int k = 0; k < 16; ++k) if (k > i) acc -= TA(k, i) * x[k];
        x[i] = acc / TA(i, i);
    }
    float4* dst = (float4*)(mleOut + (size_t)n * FGK_P);
#pragma unroll
    for (int p = 0; p < 4; ++p) dst[p] = make_float4(x[p * 4], x[p * 4 + 1], x[p * 4 + 2], x[p * 4 + 3]);
}
#undef TA

// node (16 nodes/block): a2+res -> m1 MFMA -> LN -> m2 MFMA -> hout
// + fused next-layer relu(LN(hout)) -> hinNext (doNext)
__global__ void __launch_bounds__(256)
fgkNode(const float* __restrict__ hin,
        const float* __restrict__ mleIn,
        const float* __restrict__ a2w, const float* __restrict__ a2b,
        const unsigned short* __restrict__ m1H, const unsigned short* __restrict__ m1L,
        const float* __restrict__ m1b,
        const float* __restrict__ gamma, const float* __restrict__ beta,
        const unsigned short* __restrict__ m2H, const unsigned short* __restrict__ m2L,
        const float* __restrict__ m2b,
        float* __restrict__ hout, int addres,
        float* __restrict__ hinNext, const float* __restrict__ gN,
        const float* __restrict__ bN, int doNext)
{
    __shared__ char uniN[16384];
    __shared__ float sT[16][260];
    __shared__ float stats[16][2];
    unsigned short* ovH = (unsigned short*)uniN;
    unsigned short* ovL = (unsigned short*)uniN + 2048;
    unsigned short* t2H = (unsigned short*)uniN;
    unsigned short* t2L = (unsigned short*)uniN + 4096;
    int t = threadIdx.x, lane = t & 63, wave = t >> 6;
    int n0 = blockIdx.x * 16;

#pragma unroll
    for (int pass = 0; pass < 8; ++pass) {
        int node = pass * 2 + (t >> 7);
        int col = t & 127;
        const float* mp = mleIn + (size_t)(n0 + node) * FGK_P;
        float acc = a2b[col];
#pragma unroll
        for (int k = 0; k < 16; ++k) acc += mp[k] * a2w[k * FGK_H + col];
        acc += hin[(size_t)(n0 + node) * FGK_H + col];
        unsigned short hb = fgk_f2b(acc);
        unsigned short lb = fgk_f2b(acc - fgk_u2f(hb));
        int c = col >> 5, g = (col >> 3) & 3, jj = col & 7;
        int idx = (c * 64 + node + 16 * g) * 8 + jj;
        ovH[idx] = hb; ovL[idx] = lb;
    }
    __syncthreads();

    {
        s16x8 ah[4], al[4];
#pragma unroll
        for (int c = 0; c < 4; ++c) {
            ah[c] = *(const s16x8*)&ovH[(c * 64 + lane) * 8];
            al[c] = *(const s16x8*)&ovL[(c * 64 + lane) * 8];
        }
        int n = lane & 15, qd = lane >> 4;
#pragma unroll
        for (int i4 = 0; i4 < 4; ++i4) {
            int nt = wave + i4 * 4;
            f32x4 acc = {0.f, 0.f, 0.f, 0.f};
#pragma unroll
            for (int c = 0; c < 4; ++c) {
                size_t bidx = ((size_t)(nt * 4 + c) * 64 + lane) * 8;
                s16x8 bh = *(const s16x8*)(m1H + bidx);
                s16x8 bl = *(const s16x8*)(m1L + bidx);
                acc = __builtin_amdgcn_mfma_f32_16x16x32_bf16(al[c], bh, acc, 0, 0, 0);
                acc = __builtin_amdgcn_mfma_f32_16x16x32_bf16(ah[c], bl, acc, 0, 0, 0);
                acc = __builtin_amdgcn_mfma_f32_16x16x32_bf16(ah[c], bh, acc, 0, 0, 0);
            }
            int j = nt * 16 + n;
            float bias = m1b[j];
#pragma unroll
            for (int reg = 0; reg < 4; ++reg)
                sT[4 * qd + reg][j] = acc[reg] + bias;
        }
    }
    __syncthreads();

    {
        int node = t >> 4, seg = t & 15;
        const float* rowp = &sT[node][seg * 16];
        float s1 = 0.f, s2 = 0.f;
#pragma unroll
        for (int k = 0; k < 16; ++k) { float v = rowp[k]; s1 += v; s2 += v * v; }
#pragma unroll
        for (int off = 8; off; off >>= 1) {
            s1 += __shfl_down(s1, off, 16);
            s2 += __shfl_down(s2, off, 16);
        }
        if (seg == 0) {
            float mu = s1 * (1.f / 256.f);
            float var = s2 * (1.f / 256.f) - mu * mu;
            stats[node][0] = mu;
            stats[node][1] = rsqrtf(var + 1e-5f);
        }
    }
    __syncthreads();

    {
        int node = t >> 4, seg = t & 15;
        float mu = stats[node][0], rstd = stats[node][1];
#pragma unroll
        for (int kk = 0; kk < 16; ++kk) {
            int k = seg * 16 + kk;
            float v = sT[node][k];
            float tv = fmaxf((v - mu) * rstd * gamma[k] + beta[k], 0.f);
            unsigned short hb = fgk_f2b(tv);
            unsigned short lb = fgk_f2b(tv - fgk_u2f(hb));
            int c = k >> 5, g = (k >> 3) & 3, jj = k & 7;
            int idx = (c * 64 + node + 16 * g) * 8 + jj;
            t2H[idx] = hb; t2L[idx] = lb;
        }
    }
    __syncthreads();

    {
        s16x8 ah[8], al[8];
#pragma unroll
        for (int c = 0; c < 8; ++c) {
            ah[c] = *(const s16x8*)&t2H[(c * 64 + lane) * 8];
            al[c] = *(const s16x8*)&t2L[(c * 64 + lane) * 8];
        }
        int n = lane & 15, qd = lane >> 4;
#pragma unroll
        for (int i2 = 0; i2 < 2; ++i2) {
            int nt = wave * 2 + i2;
            f32x4 acc = {0.f, 0.f, 0.f, 0.f};
#pragma unroll
            for (int c = 0; c < 8; ++c) {
                size_t bidx = ((size_t)(nt * 8 + c) * 64 + lane) * 8;
                s16x8 bh = *(const s16x8*)(m2H + bidx);
                s16x8 bl = *(const s16x8*)(m2L + bidx);
                acc = __builtin_amdgcn_mfma_f32_16x16x32_bf16(al[c], bh, acc, 0, 0, 0);
                acc = __builtin_amdgcn_mfma_f32_16x16x32_bf16(ah[c], bl, acc, 0, 0, 0);
                acc = __builtin_amdgcn_mfma_f32_16x16x32_bf16(ah[c], bh, acc, 0, 0, 0);
            }
            int j = nt * 16 + n;
            float bias = m2b[j];
#pragma unroll
            for (int reg = 0; reg < 4; ++reg) {
                int node = 4 * qd + reg;
                size_t idx = (size_t)(n0 + node) * FGK_H + j;
                float val = acc[reg] + bias;
                float nv = addres ? (hout[idx] + val) : val;
                hout[idx] = nv;
                sT[node][j] = nv;          // park for fused next-layer LN
            }
        }
    }
    if (doNext) {                          // hinNext = relu(LN(hout, gN, bN))
        __syncthreads();
        int node = t >> 4, seg = t & 15;
        const float* rowp = &sT[node][seg * 8];
        float s1 = 0.f, s2 = 0.f;
#pragma unroll
        for (int k = 0; k < 8; ++k) { float v = rowp[k]; s1 += v; s2 += v * v; }
#pragma unroll
        for (int off = 8; off; off >>= 1) {
            s1 += __shfl_down(s1, off, 16);
            s2 += __shfl_down(s2, off, 16);
        }
        if (seg == 0) {
            float mu = s1 * (1.f / 128.f);
            float var = s2 * (1.f / 128.f) - mu * mu;
            stats[node][0] = mu;
            stats[node][1] = rsqrtf(var + 1e-5f);
        }
        __syncthreads();
        float mu = stats[node][0], rstd = stats[node][1];
#pragma unroll
        for (int kk = 0; kk < 8; ++kk) {
            int k = seg * 8 + kk;
            float v = sT[node][k];
            hinNext[(size_t)(n0 + node) * FGK_H + k] =
                fmaxf((v - mu) * rstd * gN[k] + bN[k], 0.f);
        }
    }
}

// out = relu(LN(h, g0, b0)) @ lin_w + lin_b   (f32 out)
__global__ void fgkFinal(const float* __restrict__ hsrc,
                         const float* __restrict__ gamma,
                         const float* __restrict__ beta,
                         const float* __restrict__ lw,
                         const float* __restrict__ lb,
                         float* __restrict__ outp)
{
    int n = blockIdx.x, t = threadIdx.x;   // block = 128
    __shared__ float tt[FGK_H];
    __shared__ float red[4];
    float v = hsrc[(size_t)n * FGK_H + t];
    float s1 = v, s2 = v * v;
#pragma unroll
    for (int off = 32; off; off >>= 1) { s1 += __shfl_down(s1, off); s2 += __shfl_down(s2, off); }
    int wid = t >> 6, lane = t & 63;
    if (lane == 0) { red[wid] = s1; red[2 + wid] = s2; }
    __syncthreads();
    float mu = (red[0] + red[1]) * (1.f / FGK_H);
    float var = (red[2] + red[3]) * (1.f / FGK_H) - mu * mu;
    float rstd = rsqrtf(var + 1e-5f);
    tt[t] = fmaxf((v - mu) * rstd * gamma[t] + beta[t], 0.f);
    __syncthreads();
    if (t < 112) {
        float acc = lb[t];
        for (int k = 0; k < FGK_H; k++) acc += tt[k] * lw[k * 112 + t];
        outp[(size_t)n * 112 + t] = acc;
    }
}

extern "C" void kernel_launch(void* const* d_in, const int* in_sizes, int n_in,
                              void* d_out, int out_size, void* d_ws, size_t ws_size,
                              hipStream_t stream)
{
    const float* xin  = (const float*)d_in[0];
    const float* eatt = (const float*)d_in[1];
    const int*   eidx = (const int*)d_in[2];
    const float* nEw  = (const float*)d_in[3];
    const float* nEb  = (const float*)d_in[4];
    const float* eEw  = (const float*)d_in[5];
    const float* eEb  = (const float*)d_in[6];
    const float* a1w  = (const float*)d_in[7];
    const float* a1b  = (const float*)d_in[8];
    const float* a2w  = (const float*)d_in[9];
    const float* a2b  = (const float*)d_in[10];
    const float* m1w  = (const float*)d_in[11];
    const float* m1b  = (const float*)d_in[12];
    const float* lng  = (const float*)d_in[13];
    const float* lnb  = (const float*)d_in[14];
    const float* m2w  = (const float*)d_in[15];
    const float* m2b  = (const float*)d_in[16];
    const float* ng   = (const float*)d_in[17];
    const float* nb   = (const float*)d_in[18];
    const float* lw   = (const float*)d_in[19];
    const float* lb   = (const float*)d_in[20];
    float* outp = (float*)d_out;
    const int* srcIdx = eidx;
    const int* dstIdx = eidx + FGK_NE;

    float* ws   = (float*)d_ws;
    float* hAcc = ws;                                    // NN*128
    float* hin  = hAcc + (size_t)FGK_NN * FGK_H;         // NN*128
    float* snA  = hin  + (size_t)FGK_NN * FGK_H;         // NN*16
    float* fnA  = snA  + (size_t)FGK_NN * FGK_P;         // NN*136
    float* mle  = fnA  + (size_t)FGK_NN * FGK_TRI;       // NN*16
    unsigned short* wsU = (unsigned short*)(mle + (size_t)FGK_NN * FGK_P);
    const int A1F = 40 * 512, M1F = 64 * 512, M2F = 64 * 512;
    unsigned short* a1Hi = wsU;
    unsigned short* a1Lo = a1Hi + 3 * A1F;
    unsigned short* m1Hi = a1Lo + 3 * A1F;
    unsigned short* m1Lo = m1Hi + 3 * M1F;
    unsigned short* m2Hi = m1Lo + 3 * M1F;
    unsigned short* m2Lo = m2Hi + 3 * M2F;
    int* cursor = (int*)(m2Lo + 3 * M2F);                // NN ints
    int* perm   = cursor + FGK_NN;                       // NE ints

    // dst-sorted edge permutation (edge_index constant; rebuilt every launch)
    fgkZeroI<<<(FGK_NN + 255) / 256, 256, 0, stream>>>(cursor, FGK_NN);
    fgkHist<<<(FGK_NE + 255) / 256, 256, 0, stream>>>(dstIdx, cursor);
    fgkScan<<<1, 1024, 0, stream>>>(cursor, cursor);     // in-place exclusive scan
    fgkScatterE<<<(FGK_NE + 255) / 256, 256, 0, stream>>>(dstIdx, cursor, perm);

    for (int l = 0; l < 3; l++) {
        fgkPrepW<<<40, 64, 0, stream>>>(a1w + (size_t)l * FGK_H * FGK_F, 128, 152,
                                        a1Hi + l * A1F, a1Lo + l * A1F);
        fgkPrepW<<<64, 64, 0, stream>>>(m1w + (size_t)l * FGK_H * 256, 128, 256,
                                        m1Hi + l * M1F, m1Lo + l * M1F);
        fgkPrepW<<<64, 64, 0, stream>>>(m2w + (size_t)l * 256 * FGK_H, 256, 128,
                                        m2Hi + l * M2F, m2Lo + l * M2F);
    }
    fgkEnc<<<(FGK_NN * FGK_H + 255) / 256, 256, 0, stream>>>(xin, nEw, nEb, hin);
    for (int l = 0; l < 3; l++) {
        fgkZero<<<(FGK_NN * (FGK_P + FGK_TRI) + 255) / 256, 256, 0, stream>>>(snA);
        fgkEdge<<<FGK_NE / FGK_EPB, 256, 0, stream>>>(eatt, srcIdx, dstIdx, perm, eEw, eEb,
            a1Hi + l * A1F, a1Lo + l * A1F, a1b + (size_t)l * FGK_F, hin, snA, fnA);
        fgkSolve<<<(FGK_NN + 255) / 256, 256, 0, stream>>>(snA, fnA, mle);
        fgkNode<<<FGK_NN / 16, 256, 0, stream>>>(hin, mle,
            a2w + (size_t)l * FGK_P * FGK_H, a2b + (size_t)l * FGK_H,
            m1Hi + l * M1F, m1Lo + l * M1F, m1b + (size_t)l * 256,
            lng + (size_t)l * 256, lnb + (size_t)l * 256,
            m2Hi + l * M2F, m2Lo + l * M2F, m2b + (size_t)l * FGK_H,
            hAcc, l > 0 ? 1 : 0,
            hin, ng + (l + 1) * FGK_H, nb + (l + 1) * FGK_H, l < 2 ? 1 : 0);
    }
    fgkFinal<<<FGK_NN, FGK_H, 0, stream>>>(hAcc, ng, nb, lw, lb, outp);
}